// Round 8
// baseline (130.760 us; speedup 1.0000x reference)
//
#include <hip/hip_runtime.h>
#include <math.h>

// Problem constants: B=4, S=2048, D_IN=1024, D_OUT=1024, E=8, K=2
#define TOKENS 8192
#define DIN    1024
#define DOUT   1024
#define NE     8

typedef float vf4 __attribute__((ext_vector_type(4)));

// One wave per token, ZERO shared state: no LDS, no __syncthreads. gate_w
// (32 KB) and the 16 reachable expert rows (64 KB) are L2-resident in every
// XCD; per-XCD L2 read traffic is ~16 MB (~2 us) — cheaper than the barrier
// phase-lock that LDS staging forced. 2048 blocks x 256 threads (4 waves),
// launch_bounds(256,8) pins VGPR<=64 so all 32 waves/CU are resident; every
// wave runs its read->gate->select->value->write chain independently, so the
// 8192 chains self-pipeline across the CU.
__global__ __launch_bounds__(256, 8) void moe_fused(
    const float* __restrict__ x,             // [TOKENS][DIN]
    const float* __restrict__ gate_w,        // [NE][DIN]
    const float* __restrict__ gate_b,        // [NE]
    const float* __restrict__ expert_biases, // [NE]
    const float* __restrict__ expert_w,      // [NE][DOUT][DIN]
    const float* __restrict__ expert_b,      // [NE][DOUT]
    float* __restrict__ out,                 // [TOKENS][DOUT]
    float* __restrict__ out_idx) {           // [TOKENS][2] (indices as f32)
  const int t    = blockIdx.x * 4 + (threadIdx.x >> 6);  // token == wave id
  const int lane = threadIdx.x & 63;

  // ---- x row (the only HBM stream): 4 coalesced dwordx4 per lane ----
  vf4 xa[4];
  const vf4* xr = (const vf4*)(x + (size_t)t * DIN);
#pragma unroll
  for (int i = 0; i < 4; ++i) xa[i] = xr[lane + 64 * i];

  // ---- gate logits, stage-major from global (L2-hot): per x-segment issue
  //      all 8 expert-row loads back-to-back, then 32 FMAs ----
  float za[NE];
#pragma unroll
  for (int e = 0; e < NE; ++e) za[e] = 0.f;
#pragma unroll
  for (int i = 0; i < 4; ++i) {
    vf4 w[NE];
#pragma unroll
    for (int e = 0; e < NE; ++e)
      w[e] = ((const vf4*)(gate_w + e * DIN))[lane + 64 * i];
#pragma unroll
    for (int e = 0; e < NE; ++e)
      za[e] += xa[i].x * w[e].x + xa[i].y * w[e].y + xa[i].z * w[e].z + xa[i].w * w[e].w;
  }

  // ---- butterfly reduce, stage-major: 8 independent shuffles per stage ----
#pragma unroll
  for (int off = 32; off > 0; off >>= 1) {
    float tmp[NE];
#pragma unroll
    for (int e = 0; e < NE; ++e) tmp[e] = __shfl_xor(za[e], off, 64);
#pragma unroll
    for (int e = 0; e < NE; ++e) za[e] += tmp[e];
  }
#pragma unroll
  for (int e = 0; e < NE; ++e) za[e] += gate_b[e] + expert_biases[e];

  // ---- top-2 on logits (sigmoid monotone -> identical indices & tie order) ----
  int e0 = 0; float z0 = za[0];
#pragma unroll
  for (int e = 1; e < NE; ++e) if (za[e] > z0) { z0 = za[e]; e0 = e; }
  int e1 = (e0 == 0) ? 1 : 0; float z1 = za[e1];
#pragma unroll
  for (int e = 0; e < NE; ++e) if (e != e0 && za[e] > z1) { z1 = za[e]; e1 = e; }

  if (lane == 0) {  // retire the tiny index stores early
    out_idx[t * 2 + 0] = (float)e0;
    out_idx[t * 2 + 1] = (float)e1;
  }

  // ---- both selected value rows (64 KB L2-hot set), issued together ----
  const vf4* r0 = (const vf4*)(expert_w + (size_t)e0 * (DOUT * DIN));        // w[e0][0][:]
  const vf4* r1 = (const vf4*)(expert_w + (size_t)e1 * (DOUT * DIN) + DIN);  // w[e1][1][:]
  vf4 wa[4], wb[4];
#pragma unroll
  for (int i = 0; i < 4; ++i) { wa[i] = r0[lane + 64 * i]; wb[i] = r1[lane + 64 * i]; }
  float b0 = expert_b[e0 * DOUT + 0];
  float b1 = expert_b[e1 * DOUT + 1];

  // sigmoid + normalize overlaps the value-row loads
  float p0 = 1.f / (1.f + expf(-z0));
  float p1 = 1.f / (1.f + expf(-z1));
  float s  = 1.f / (p0 + p1);
  float w0 = p0 * s, w1 = p1 * s;

  float d0 = 0.f, d1 = 0.f;
#pragma unroll
  for (int i = 0; i < 4; ++i) {
    d0 += xa[i].x * wa[i].x + xa[i].y * wa[i].y + xa[i].z * wa[i].z + xa[i].w * wa[i].w;
    d1 += xa[i].x * wb[i].x + xa[i].y * wb[i].y + xa[i].z * wb[i].z + xa[i].w * wb[i].w;
  }
#pragma unroll
  for (int off = 32; off > 0; off >>= 1) {
    float t0v = __shfl_xor(d0, off, 64);
    float t1v = __shfl_xor(d1, off, 64);
    d0 += t0v; d1 += t1v;
  }
  d0 += b0; d1 += b1;

  float ov = d0 * w0 + d1 * w1;

  // ---- broadcast store: out[t,:] = weighted scalar (4 KB row / wave) ----
  vf4 v = {ov, ov, ov, ov};
  vf4* orow = (vf4*)(out + (size_t)t * DOUT);
#pragma unroll
  for (int i = 0; i < 4; ++i) orow[lane + 64 * i] = v;
}

extern "C" void kernel_launch(void* const* d_in, const int* in_sizes, int n_in,
                              void* d_out, int out_size, void* d_ws, size_t ws_size,
                              hipStream_t stream) {
  const float* x             = (const float*)d_in[0];
  const float* gate_w        = (const float*)d_in[1];
  const float* gate_b        = (const float*)d_in[2];
  const float* expert_biases = (const float*)d_in[3];
  const float* expert_w      = (const float*)d_in[4];
  const float* expert_b      = (const float*)d_in[5];

  float* out     = (float*)d_out;
  float* out_idx = out + (size_t)TOKENS * DOUT;  // second tuple output, flat-concatenated

  // 2048 blocks x 256 threads (4 waves) x 1 token/wave = 8192 tokens exact.
  moe_fused<<<dim3(2048), dim3(256), 0, stream>>>(
      x, gate_w, gate_b, expert_biases, expert_w, expert_b, out, out_idx);
}

// Round 10
// 123.435 us; speedup vs baseline: 1.0593x; 1.0593x over previous
//
#include <hip/hip_runtime.h>
#include <math.h>

// Problem constants: B=4, S=2048, D_IN=1024, D_OUT=1024, E=8, K=2
#define TOKENS 8192
#define DIN    1024
#define DOUT   1024
#define NE     8

typedef float vf4 __attribute__((ext_vector_type(4)));

// R5 structure (best measured: fused, LDS gate, 1 token/wave, 32 waves/CU,
// stage-major issue) with cheap reductions:
//  - gate reduce: fold 8 partials via xor-32/16/8 (4+2+1 shuffles), butterfly
//    xor-4/2/1 (3), gather via 8 const-lane shuffles -> 18 ops vs 48.
//  - value reduce: weight per-lane partials with wave-uniform w0/w1 first,
//    then ONE 6-stage butterfly -> 6 ops vs 12.
// launch_bounds(512,8): VGPR<=64 -> 4 blocks/CU, full 32 waves/CU.
__global__ __launch_bounds__(512, 8) void moe_fused(
    const float* __restrict__ x,             // [TOKENS][DIN]
    const float* __restrict__ gate_w,        // [NE][DIN]
    const float* __restrict__ gate_b,        // [NE]
    const float* __restrict__ expert_biases, // [NE]
    const float* __restrict__ expert_w,      // [NE][DOUT][DIN]
    const float* __restrict__ expert_b,      // [NE][DOUT]
    float* __restrict__ out,                 // [TOKENS][DOUT]
    float* __restrict__ out_idx) {           // [TOKENS][2] (indices as f32)
  __shared__ float lgate[NE * DIN];  // 32 KB f32 (selection must be f32-exact)

  {
    const vf4* src = (const vf4*)gate_w;
    vf4* dst = (vf4*)lgate;
#pragma unroll
    for (int i = 0; i < 4; ++i)
      dst[threadIdx.x + 512 * i] = src[threadIdx.x + 512 * i];
  }

  const int t    = blockIdx.x * 8 + (threadIdx.x >> 6);  // token == wave id
  const int lane = threadIdx.x & 63;
  const int my_e = (lane >> 3) & 7;  // expert this lane owns after the fold

  // x loads + per-lane expert bias issued before the barrier: latency hides
  // under the vmcnt(0)+s_barrier drain of __syncthreads.
  vf4 xa[4];
  const vf4* xr = (const vf4*)(x + (size_t)t * DIN);
#pragma unroll
  for (int i = 0; i < 4; ++i) xa[i] = xr[lane + 64 * i];
  float bias_e = gate_b[my_e] + expert_biases[my_e];

  __syncthreads();

  // ---- gate partials, stage-major: per segment issue all 8 LDS reads ----
  float za[NE];
#pragma unroll
  for (int e = 0; e < NE; ++e) za[e] = 0.f;
#pragma unroll
  for (int i = 0; i < 4; ++i) {
    vf4 w[NE];
#pragma unroll
    for (int e = 0; e < NE; ++e)
      w[e] = ((const vf4*)(lgate + e * DIN))[lane + 64 * i];
#pragma unroll
    for (int e = 0; e < NE; ++e)
      za[e] += xa[i].x * w[e].x + xa[i].y * w[e].y + xa[i].z * w[e].z + xa[i].w * w[e].w;
  }

  // ---- fold reduction: 8 sums over 64 lanes in 7 shuffles + 3 butterfly ----
  // Stage A (xor 32): 8 -> 4 values/lane; hi lanes keep experts +4.
  {
    float r[4];
#pragma unroll
    for (int j = 0; j < 4; ++j) {
      float send = (lane & 32) ? za[j] : za[j + 4];
      r[j] = __shfl_xor(send, 32, 64);
    }
#pragma unroll
    for (int j = 0; j < 4; ++j) za[j] = ((lane & 32) ? za[j + 4] : za[j]) + r[j];
  }
  // Stage B (xor 16): 4 -> 2; bit4 lanes keep experts +2.
  {
    float r[2];
#pragma unroll
    for (int j = 0; j < 2; ++j) {
      float send = (lane & 16) ? za[j] : za[j + 2];
      r[j] = __shfl_xor(send, 16, 64);
    }
#pragma unroll
    for (int j = 0; j < 2; ++j) za[j] = ((lane & 16) ? za[j + 2] : za[j]) + r[j];
  }
  // Stage C (xor 8): 2 -> 1; bit3 lanes keep experts +1.
  float zf;
  {
    float send = (lane & 8) ? za[0] : za[1];
    float rr = __shfl_xor(send, 8, 64);
    zf = ((lane & 8) ? za[1] : za[0]) + rr;
  }
  // Butterfly over bits 0-2: full 64-lane sum for this lane's expert.
#pragma unroll
  for (int off = 4; off > 0; off >>= 1) zf += __shfl_xor(zf, off, 64);
  zf += bias_e;

  // ---- gather all 8 logits (lane 8e holds expert e; const-lane shuffles
  //      lower to readlane broadcasts) ----
  float g[NE];
#pragma unroll
  for (int e = 0; e < NE; ++e) g[e] = __shfl(zf, e * 8, 64);

  // ---- top-2 (sigmoid monotone -> identical indices; strict > = lax ties) ----
  int e0 = 0; float z0 = g[0];
#pragma unroll
  for (int e = 1; e < NE; ++e) if (g[e] > z0) { z0 = g[e]; e0 = e; }
  int e1 = (e0 == 0) ? 1 : 0; float z1 = g[e1];
#pragma unroll
  for (int e = 0; e < NE; ++e) if (e != e0 && g[e] > z1) { z1 = g[e]; e1 = e; }

  if (lane == 0) {  // retire tiny index stores early
    out_idx[t * 2 + 0] = (float)e0;
    out_idx[t * 2 + 1] = (float)e1;
  }

  // ---- both selected value rows (64 KB L2-hot set), issued together ----
  const vf4* r0 = (const vf4*)(expert_w + (size_t)e0 * (DOUT * DIN));        // w[e0][0][:]
  const vf4* r1 = (const vf4*)(expert_w + (size_t)e1 * (DOUT * DIN) + DIN);  // w[e1][1][:]
  vf4 wa[4], wb[4];
#pragma unroll
  for (int i = 0; i < 4; ++i) { wa[i] = r0[lane + 64 * i]; wb[i] = r1[lane + 64 * i]; }
  float b0 = expert_b[e0 * DOUT + 0];
  float b1 = expert_b[e1 * DOUT + 1];

  // wave-uniform weights (overlap the value-row loads)
  float p0 = 1.f / (1.f + expf(-z0));
  float p1 = 1.f / (1.f + expf(-z1));
  float s  = 1.f / (p0 + p1);
  float w0 = p0 * s, w1 = p1 * s;

  // per-lane weighted partial, then ONE butterfly
  float ovp = 0.f;
#pragma unroll
  for (int i = 0; i < 4; ++i) {
    float d0p = xa[i].x * wa[i].x + xa[i].y * wa[i].y + xa[i].z * wa[i].z + xa[i].w * wa[i].w;
    float d1p = xa[i].x * wb[i].x + xa[i].y * wb[i].y + xa[i].z * wb[i].z + xa[i].w * wb[i].w;
    ovp += d0p * w0 + d1p * w1;
  }
#pragma unroll
  for (int off = 32; off > 0; off >>= 1) ovp += __shfl_xor(ovp, off, 64);
  float ov = ovp + b0 * w0 + b1 * w1;

  // ---- broadcast store: out[t,:] = weighted scalar (4 KB row / wave) ----
  vf4 v = {ov, ov, ov, ov};
  vf4* orow = (vf4*)(out + (size_t)t * DOUT);
#pragma unroll
  for (int i = 0; i < 4; ++i) orow[lane + 64 * i] = v;
}

extern "C" void kernel_launch(void* const* d_in, const int* in_sizes, int n_in,
                              void* d_out, int out_size, void* d_ws, size_t ws_size,
                              hipStream_t stream) {
  const float* x             = (const float*)d_in[0];
  const float* gate_w        = (const float*)d_in[1];
  const float* gate_b        = (const float*)d_in[2];
  const float* expert_biases = (const float*)d_in[3];
  const float* expert_w      = (const float*)d_in[4];
  const float* expert_b      = (const float*)d_in[5];

  float* out     = (float*)d_out;
  float* out_idx = out + (size_t)TOKENS * DOUT;  // second tuple output, flat-concatenated

  // 1024 blocks x 512 threads (8 waves) x 1 token/wave = 8192 tokens exact.
  moe_fused<<<dim3(1024), dim3(512), 0, stream>>>(
      x, gate_w, gate_b, expert_biases, expert_w, expert_b, out, out_idx);
}

// Round 11
// 110.569 us; speedup vs baseline: 1.1826x; 1.1164x over previous
//
#include <hip/hip_runtime.h>
#include <math.h>

// Problem constants: B=4, S=2048, D_IN=1024, D_OUT=1024, E=8, K=2
#define TOKENS 8192
#define DIN    1024
#define DOUT   1024
#define NE     8
#define NWAVES 4096   // 512 blocks x 8 waves; each wave does tokens w and w+NWAVES

typedef float vf4 __attribute__((ext_vector_type(4)));

// 2-round software-pipelined version of the measured-best R5 structure:
// fused, LDS-staged f32 gate, stage-major issue, butterfly gate reduce.
// Each wave handles token w, then token w+4096. Round-2's x load is issued
// ~2000 cycles early (during round-1 compute), so round-2 HBM reads overlap
// round-1 value/store, and round-1's row store drains under round-2's gate
// LDS phase — merging the pure-read head and pure-write tail that made the
// single-round version a lockstep phase-train.
__global__ __launch_bounds__(512, 4) void moe_fused(
    const float* __restrict__ x,             // [TOKENS][DIN]
    const float* __restrict__ gate_w,        // [NE][DIN]
    const float* __restrict__ gate_b,        // [NE]
    const float* __restrict__ expert_biases, // [NE]
    const float* __restrict__ expert_w,      // [NE][DOUT][DIN]
    const float* __restrict__ expert_b,      // [NE][DOUT]
    float* __restrict__ out,                 // [TOKENS][DOUT]
    float* __restrict__ out_idx) {           // [TOKENS][2] (indices as f32)
  __shared__ float lgate[NE * DIN];  // 32 KB f32 (selection must be f32-exact)

  {
    const vf4* src = (const vf4*)gate_w;
    vf4* dst = (vf4*)lgate;
#pragma unroll
    for (int i = 0; i < 4; ++i)
      dst[threadIdx.x + 512 * i] = src[threadIdx.x + 512 * i];
  }

  const int w    = blockIdx.x * 8 + (threadIdx.x >> 6);
  const int lane = threadIdx.x & 63;
  const int t0 = w;
  const int t1 = w + NWAVES;

  // wave-uniform gate biases, loaded once, reused for both tokens
  float zbias[NE];
#pragma unroll
  for (int e = 0; e < NE; ++e) zbias[e] = gate_b[e] + expert_biases[e];

  // round-0 x issued before the barrier (latency hides under barrier drain)
  vf4 xa[4];
  const vf4* xr0 = (const vf4*)(x + (size_t)t0 * DIN);
#pragma unroll
  for (int i = 0; i < 4; ++i) xa[i] = xr0[lane + 64 * i];

  __syncthreads();

  // ================= round 0: token t0 =================
  float za[NE];
#pragma unroll
  for (int e = 0; e < NE; ++e) za[e] = 0.f;
#pragma unroll
  for (int i = 0; i < 4; ++i) {
    vf4 wv[NE];
#pragma unroll
    for (int e = 0; e < NE; ++e)
      wv[e] = ((const vf4*)(lgate + e * DIN))[lane + 64 * i];
#pragma unroll
    for (int e = 0; e < NE; ++e)
      za[e] += xa[i].x * wv[e].x + xa[i].y * wv[e].y + xa[i].z * wv[e].z + xa[i].w * wv[e].w;
  }

  // ---- prefetch round-1 x NOW: independent, ~2000 cycles before first use ----
  vf4 xb[4];
  const vf4* xr1 = (const vf4*)(x + (size_t)t1 * DIN);
#pragma unroll
  for (int i = 0; i < 4; ++i) xb[i] = xr1[lane + 64 * i];

  // butterfly reduce (stage-major: 8 independent shuffles per stage)
#pragma unroll
  for (int off = 32; off > 0; off >>= 1) {
    float tmp[NE];
#pragma unroll
    for (int e = 0; e < NE; ++e) tmp[e] = __shfl_xor(za[e], off, 64);
#pragma unroll
    for (int e = 0; e < NE; ++e) za[e] += tmp[e];
  }
#pragma unroll
  for (int e = 0; e < NE; ++e) za[e] += zbias[e];

  int e0 = 0; float z0 = za[0];
#pragma unroll
  for (int e = 1; e < NE; ++e) if (za[e] > z0) { z0 = za[e]; e0 = e; }
  int e1 = (e0 == 0) ? 1 : 0; float z1 = za[e1];
#pragma unroll
  for (int e = 0; e < NE; ++e) if (e != e0 && za[e] > z1) { z1 = za[e]; e1 = e; }

  if (lane == 0) {
    out_idx[t0 * 2 + 0] = (float)e0;
    out_idx[t0 * 2 + 1] = (float)e1;
  }

  {
    const vf4* r0 = (const vf4*)(expert_w + (size_t)e0 * (DOUT * DIN));        // w[e0][0][:]
    const vf4* r1 = (const vf4*)(expert_w + (size_t)e1 * (DOUT * DIN) + DIN);  // w[e1][1][:]
    vf4 wa[4], wb[4];
#pragma unroll
    for (int i = 0; i < 4; ++i) { wa[i] = r0[lane + 64 * i]; wb[i] = r1[lane + 64 * i]; }
    float b0 = expert_b[e0 * DOUT + 0];
    float b1 = expert_b[e1 * DOUT + 1];

    float p0 = 1.f / (1.f + expf(-z0));
    float p1 = 1.f / (1.f + expf(-z1));
    float s  = 1.f / (p0 + p1);
    float w0 = p0 * s, w1 = p1 * s;

    // per-lane weighted partial, one butterfly (w0/w1 wave-uniform)
    float ovp = 0.f;
#pragma unroll
    for (int i = 0; i < 4; ++i) {
      float d0p = xa[i].x * wa[i].x + xa[i].y * wa[i].y + xa[i].z * wa[i].z + xa[i].w * wa[i].w;
      float d1p = xa[i].x * wb[i].x + xa[i].y * wb[i].y + xa[i].z * wb[i].z + xa[i].w * wb[i].w;
      ovp += d0p * w0 + d1p * w1;
    }
#pragma unroll
    for (int off = 32; off > 0; off >>= 1) ovp += __shfl_xor(ovp, off, 64);
    float ov = ovp + b0 * w0 + b1 * w1;

    vf4 v = {ov, ov, ov, ov};
    vf4* orow = (vf4*)(out + (size_t)t0 * DOUT);
#pragma unroll
    for (int i = 0; i < 4; ++i) orow[lane + 64 * i] = v;  // drains under round-1 DS work
  }

  // ================= round 1: token t1 (xb already in flight/resident) =================
#pragma unroll
  for (int e = 0; e < NE; ++e) za[e] = 0.f;
#pragma unroll
  for (int i = 0; i < 4; ++i) {
    vf4 wv[NE];
#pragma unroll
    for (int e = 0; e < NE; ++e)
      wv[e] = ((const vf4*)(lgate + e * DIN))[lane + 64 * i];
#pragma unroll
    for (int e = 0; e < NE; ++e)
      za[e] += xb[i].x * wv[e].x + xb[i].y * wv[e].y + xb[i].z * wv[e].z + xb[i].w * wv[e].w;
  }

#pragma unroll
  for (int off = 32; off > 0; off >>= 1) {
    float tmp[NE];
#pragma unroll
    for (int e = 0; e < NE; ++e) tmp[e] = __shfl_xor(za[e], off, 64);
#pragma unroll
    for (int e = 0; e < NE; ++e) za[e] += tmp[e];
  }
#pragma unroll
  for (int e = 0; e < NE; ++e) za[e] += zbias[e];

  int f0 = 0; float y0 = za[0];
#pragma unroll
  for (int e = 1; e < NE; ++e) if (za[e] > y0) { y0 = za[e]; f0 = e; }
  int f1 = (f0 == 0) ? 1 : 0; float y1 = za[f1];
#pragma unroll
  for (int e = 0; e < NE; ++e) if (e != f0 && za[e] > y1) { y1 = za[e]; f1 = e; }

  if (lane == 0) {
    out_idx[t1 * 2 + 0] = (float)f0;
    out_idx[t1 * 2 + 1] = (float)f1;
  }

  {
    const vf4* r0 = (const vf4*)(expert_w + (size_t)f0 * (DOUT * DIN));
    const vf4* r1 = (const vf4*)(expert_w + (size_t)f1 * (DOUT * DIN) + DIN);
    vf4 wa[4], wb[4];
#pragma unroll
    for (int i = 0; i < 4; ++i) { wa[i] = r0[lane + 64 * i]; wb[i] = r1[lane + 64 * i]; }
    float b0 = expert_b[f0 * DOUT + 0];
    float b1 = expert_b[f1 * DOUT + 1];

    float p0 = 1.f / (1.f + expf(-y0));
    float p1 = 1.f / (1.f + expf(-y1));
    float s  = 1.f / (p0 + p1);
    float w0 = p0 * s, w1 = p1 * s;

    float ovp = 0.f;
#pragma unroll
    for (int i = 0; i < 4; ++i) {
      float d0p = xb[i].x * wa[i].x + xb[i].y * wa[i].y + xb[i].z * wa[i].z + xb[i].w * wa[i].w;
      float d1p = xb[i].x * wb[i].x + xb[i].y * wb[i].y + xb[i].z * wb[i].z + xb[i].w * wb[i].w;
      ovp += d0p * w0 + d1p * w1;
    }
#pragma unroll
    for (int off = 32; off > 0; off >>= 1) ovp += __shfl_xor(ovp, off, 64);
    float ov = ovp + b0 * w0 + b1 * w1;

    vf4 v = {ov, ov, ov, ov};
    vf4* orow = (vf4*)(out + (size_t)t1 * DOUT);
#pragma unroll
    for (int i = 0; i < 4; ++i) orow[lane + 64 * i] = v;
  }
}

extern "C" void kernel_launch(void* const* d_in, const int* in_sizes, int n_in,
                              void* d_out, int out_size, void* d_ws, size_t ws_size,
                              hipStream_t stream) {
  const float* x             = (const float*)d_in[0];
  const float* gate_w        = (const float*)d_in[1];
  const float* gate_b        = (const float*)d_in[2];
  const float* expert_biases = (const float*)d_in[3];
  const float* expert_w      = (const float*)d_in[4];
  const float* expert_b      = (const float*)d_in[5];

  float* out     = (float*)d_out;
  float* out_idx = out + (size_t)TOKENS * DOUT;  // second tuple output, flat-concatenated

  // 512 blocks x 512 threads (8 waves) x 2 sequential tokens/wave = 8192 tokens.
  moe_fused<<<dim3(512), dim3(512), 0, stream>>>(
      x, gate_w, gate_b, expert_biases, expert_w, expert_b, out, out_idx);
}